// Round 5
// baseline (278.622 us; speedup 1.0000x reference)
//
#include <hip/hip_runtime.h>

#define NN 8192
#define INF_ 512
#define OUTF 256
#define LOG2E 1.4426950408889634f

typedef __attribute__((ext_vector_type(8))) short short8;
typedef __attribute__((ext_vector_type(4))) float f4;
typedef __attribute__((ext_vector_type(4))) int i4;

__device__ __forceinline__ unsigned short f2bf(float f) {
  union { float f; unsigned u; } v; v.f = f;
  unsigned r = v.u + 0x7fffu + ((v.u >> 16) & 1u);
  return (unsigned short)(r >> 16);
}
__device__ __forceinline__ float bf2f(unsigned short h) {
  union { unsigned u; float f; } v; v.u = ((unsigned)h) << 16;
  return v.f;
}

// ---------------- K0: W (512x256 f32) -> W^T hi/lo bf16 (256x512) ----------------
__global__ void k_wsplit(const float* __restrict__ W, unsigned short* __restrict__ Whi,
                         unsigned short* __restrict__ Wlo) {
  int idx = blockIdx.x * 256 + threadIdx.x;   // 131072
  int k = idx >> 8, c = idx & 255;
  float w = W[idx];
  unsigned short hi = f2bf(w);
  unsigned short lo = f2bf(w - bf2f(hi));
  Whi[c * INF_ + k] = hi;
  Wlo[c * INF_ + k] = lo;
}

// ---------------- K1: h = x@W (split-3 bf16 MFMA), h_T bf16, s1, s2 ----------------
// 512 blocks x 1 wave; block b: rows [b*16,+16), ALL 256 cols. a pre-scaled by LOG2E.
__global__ void __launch_bounds__(64) k_h(
    const float* __restrict__ x, const float* __restrict__ a,
    const unsigned short* __restrict__ Whi, const unsigned short* __restrict__ Wlo,
    unsigned short* __restrict__ hT, float* __restrict__ s1, float* __restrict__ s2) {
  const int rowbase = blockIdx.x * 16;
  const int l = threadIdx.x;
  const int r15 = l & 15, kg = l >> 4;

  f4 acc[16];
#pragma unroll
  for (int i = 0; i < 16; ++i) acc[i] = (f4){0.f, 0.f, 0.f, 0.f};

  for (int kk = 0; kk < INF_; kk += 32) {
    const float* xp = x + (rowbase + r15) * INF_ + kk + kg * 8;
    f4 xa = *(const f4*)xp;
    f4 xb = *(const f4*)(xp + 4);
    short8 ahi, alo;
#pragma unroll
    for (int e = 0; e < 8; ++e) {
      float f = (e < 4) ? xa[e] : xb[e - 4];
      unsigned short h = f2bf(f);
      ahi[e] = (short)h;
      alo[e] = (short)f2bf(f - bf2f(h));
    }
#pragma unroll
    for (int cg = 0; cg < 16; ++cg) {
      int col = cg * 16 + r15;
      const short8 bhi = *(const short8*)(Whi + col * INF_ + kk + kg * 8);
      const short8 blo = *(const short8*)(Wlo + col * INF_ + kk + kg * 8);
      acc[cg] = __builtin_amdgcn_mfma_f32_16x16x32_bf16(ahi, bhi, acc[cg], 0, 0, 0);
      acc[cg] = __builtin_amdgcn_mfma_f32_16x16x32_bf16(ahi, blo, acc[cg], 0, 0, 0);
      acc[cg] = __builtin_amdgcn_mfma_f32_16x16x32_bf16(alo, bhi, acc[cg], 0, 0, 0);
    }
  }
  float sp1[4] = {0, 0, 0, 0}, sp2[4] = {0, 0, 0, 0};
#pragma unroll
  for (int cg = 0; cg < 16; ++cg) {
    int col = cg * 16 + r15;
    float a1v = a[col] * LOG2E, a2v = a[OUTF + col] * LOG2E;
#pragma unroll
    for (int r = 0; r < 4; ++r) {
      float v = acc[cg][r];
      hT[col * NN + rowbase + kg * 4 + r] = f2bf(v);
      sp1[r] += v * a1v;
      sp2[r] += v * a2v;
    }
  }
#pragma unroll
  for (int r = 0; r < 4; ++r) {
#pragma unroll
    for (int m = 1; m < 16; m <<= 1) {
      sp1[r] += __shfl_xor(sp1[r], m, 16);
      sp2[r] += __shfl_xor(sp2[r], m, 16);
    }
    if (r15 == 0) {
      s1[rowbase + kg * 4 + r] = sp1[r];
      s2[rowbase + kg * 4 + r] = sp2[r];
    }
  }
}

// ---------------- K2: fused mask + exp + (attention-partial @ h), barrier-free ----------------
// 1024 single-wave blocks: chunk=b&3 (2048-j, XCD-aligned), rows (b>>2)*32..+32.
// 64 iters of j=32. Per iter ISSUE ORDER (the whole point): B(t+1) first, then
// adj(t+2) -- so the MFMA's wait for B(t) (older than adj(t+1)) never forces
// adj prefetches to retire, and adj always has ~2 iters of flight. Ping-pong
// NAMED register sets via x2 unroll; empty asm "memory" fences pin load groups.
// Plain stores to chunk-partial buffers; no atomics, no LDS, no barriers.
__global__ void __launch_bounds__(64, 1) k_attn(
    const int* __restrict__ adj, const float* __restrict__ s1G,
    const float* __restrict__ s2G, const unsigned short* __restrict__ hT,
    float* __restrict__ accP, float* __restrict__ lGp) {
  const int b = blockIdx.x;
  const int chunk = b & 3;
  const int rowbase = (b >> 2) * 32;
  const int l = threadIdx.x;
  const int r15 = l & 15, kg = l >> 4;
  const int row0 = rowbase + r15, row1 = rowbase + 16 + r15;
  const int jchunk = chunk * 2048;

  const float s1_0 = s1G[row0];   // pre-scaled by LOG2E
  const float s1_1 = s1G[row1];

  const int* ap0 = adj + row0 * NN + jchunk + kg * 8;
  const int* ap1 = adj + row1 * NN + jchunk + kg * 8;
  const float* sp = s2G + jchunk + kg * 8;
  const unsigned short* hp = hT + jchunk + kg * 8;

  f4 acc0[16], acc1[16];
#pragma unroll
  for (int c = 0; c < 16; ++c) {
    acc0[c] = (f4){0.f, 0.f, 0.f, 0.f};
    acc1[c] = (f4){0.f, 0.f, 0.f, 0.f};
  }
  float lsum0 = 0.f, lsum1 = 0.f;

  short8 BE[16], BO[16];
  i4 aE[4], aO[4];
  f4 sE[2], sO[2];

  // ---- prologue: B(0) -> BE ; adj(0) -> aE/sE ; adj(1) -> aO/sO ----
#pragma unroll
  for (int cg = 0; cg < 16; ++cg)
    BE[cg] = *(const short8*)(hp + (cg * 16 + r15) * NN);
  aE[0] = *(const i4*)(ap0);      aE[1] = *(const i4*)(ap0 + 4);
  aE[2] = *(const i4*)(ap1);      aE[3] = *(const i4*)(ap1 + 4);
  sE[0] = *(const f4*)(sp);       sE[1] = *(const f4*)(sp + 4);
  aO[0] = *(const i4*)(ap0 + 32); aO[1] = *(const i4*)(ap0 + 36);
  aO[2] = *(const i4*)(ap1 + 32); aO[3] = *(const i4*)(ap1 + 36);
  sO[0] = *(const f4*)(sp + 32);  sO[1] = *(const f4*)(sp + 36);
  asm volatile("" ::: "memory");

#define W_COMPUTE(AA, SS, AF0, AF1)                                          \
  {                                                                          \
    _Pragma("unroll")                                                        \
    for (int e = 0; e < 8; ++e) {                                            \
      float sv = (e < 4) ? SS[0][e] : SS[1][e - 4];                          \
      int m0 = (e < 4) ? AA[0][e] : AA[1][e - 4];                            \
      int m1 = (e < 4) ? AA[2][e] : AA[3][e - 4];                            \
      float x0 = s1_0 + sv, x1 = s1_1 + sv;                                  \
      float lr0 = fmaxf(x0, 0.2f * x0);                                      \
      float lr1 = fmaxf(x1, 0.2f * x1);                                      \
      float p0 = __builtin_amdgcn_exp2f(lr0);                                \
      float p1 = __builtin_amdgcn_exp2f(lr1);                                \
      float w0 = (m0 > 0) ? p0 : 0.0f;                                       \
      float w1 = (m1 > 0) ? p1 : 0.0f;                                       \
      unsigned short h0 = f2bf(w0), h1 = f2bf(w1);                           \
      AF0[e] = (short)h0; AF1[e] = (short)h1;                                \
      lsum0 += bf2f(h0); lsum1 += bf2f(h1);                                  \
    }                                                                        \
  }

  for (int tt = 0; tt < 64; tt += 2) {
    // ======== even half: consume tile tt (BE, aE/sE) ========
    {
      const int tB = (tt + 1 <= 63) ? tt + 1 : 63;     // B(t+1) -> BO (issue FIRST)
#pragma unroll
      for (int cg = 0; cg < 16; ++cg)
        BO[cg] = *(const short8*)(hp + (cg * 16 + r15) * NN + tB * 32);
      asm volatile("" ::: "memory");
      short8 af0, af1;
      W_COMPUTE(aE, sE, af0, af1)
      const int tA = (tt + 2 <= 63) ? tt + 2 : 63;     // adj(t+2) -> aE/sE (issue SECOND)
      aE[0] = *(const i4*)(ap0 + tA * 32); aE[1] = *(const i4*)(ap0 + tA * 32 + 4);
      aE[2] = *(const i4*)(ap1 + tA * 32); aE[3] = *(const i4*)(ap1 + tA * 32 + 4);
      sE[0] = *(const f4*)(sp + tA * 32);  sE[1] = *(const f4*)(sp + tA * 32 + 4);
      asm volatile("" ::: "memory");
#pragma unroll
      for (int cg = 0; cg < 16; ++cg) {
        acc0[cg] = __builtin_amdgcn_mfma_f32_16x16x32_bf16(af0, BE[cg], acc0[cg], 0, 0, 0);
        acc1[cg] = __builtin_amdgcn_mfma_f32_16x16x32_bf16(af1, BE[cg], acc1[cg], 0, 0, 0);
      }
    }
    // ======== odd half: consume tile tt+1 (BO, aO/sO) ========
    {
      const int tB = (tt + 2 <= 63) ? tt + 2 : 63;     // B(t+2) -> BE
#pragma unroll
      for (int cg = 0; cg < 16; ++cg)
        BE[cg] = *(const short8*)(hp + (cg * 16 + r15) * NN + tB * 32);
      asm volatile("" ::: "memory");
      short8 af0, af1;
      W_COMPUTE(aO, sO, af0, af1)
      const int tA = (tt + 3 <= 63) ? tt + 3 : 63;     // adj(t+3) -> aO/sO
      aO[0] = *(const i4*)(ap0 + tA * 32); aO[1] = *(const i4*)(ap0 + tA * 32 + 4);
      aO[2] = *(const i4*)(ap1 + tA * 32); aO[3] = *(const i4*)(ap1 + tA * 32 + 4);
      sO[0] = *(const f4*)(sp + tA * 32);  sO[1] = *(const f4*)(sp + tA * 32 + 4);
      asm volatile("" ::: "memory");
#pragma unroll
      for (int cg = 0; cg < 16; ++cg) {
        acc0[cg] = __builtin_amdgcn_mfma_f32_16x16x32_bf16(af0, BO[cg], acc0[cg], 0, 0, 0);
        acc1[cg] = __builtin_amdgcn_mfma_f32_16x16x32_bf16(af1, BO[cg], acc1[cg], 0, 0, 0);
      }
    }
  }

  // ---- epilogue: lsum reduce over kg, plain stores (no atomics) ----
  lsum0 += __shfl_xor(lsum0, 16, 64);
  lsum0 += __shfl_xor(lsum0, 32, 64);
  lsum1 += __shfl_xor(lsum1, 16, 64);
  lsum1 += __shfl_xor(lsum1, 32, 64);
  if (l < 16) {
    lGp[chunk * NN + rowbase + l] = lsum0;
    lGp[chunk * NN + rowbase + 16 + l] = lsum1;
  }
  float* accC = accP + (size_t)chunk * NN * OUTF;
#pragma unroll
  for (int cg = 0; cg < 16; ++cg)
#pragma unroll
    for (int r = 0; r < 4; ++r) {
      const int col = cg * 16 + r15;
      accC[(rowbase + kg * 4 + r) * OUTF + col] = acc0[cg][r];
      accC[(rowbase + 16 + kg * 4 + r) * OUTF + col] = acc1[cg][r];
    }
}

// ---------------- K3: out = (sum of 4 chunk-partials) / l + bias ----------------
__global__ void k_final(const float* __restrict__ accP, const float* __restrict__ lGp,
                        const float* __restrict__ bias, float* __restrict__ out) {
  const int idx = blockIdx.x * 256 + threadIdx.x;  // f4 index, 524288 total
  const int row = idx >> 6;
  const int c4 = idx & 63;
  const int CS = NN * OUTF / 4;   // chunk stride in f4
  f4 v0 = ((const f4*)accP)[idx];
  f4 v1 = ((const f4*)accP)[idx + CS];
  f4 v2 = ((const f4*)accP)[idx + 2 * CS];
  f4 v3 = ((const f4*)accP)[idx + 3 * CS];
  float lv = lGp[row] + lGp[NN + row] + lGp[2 * NN + row] + lGp[3 * NN + row];
  float inv = 1.0f / lv;
  f4 bb = ((const f4*)bias)[c4];
  f4 o;
#pragma unroll
  for (int e = 0; e < 4; ++e)
    o[e] = (v0[e] + v1[e] + v2[e] + v3[e]) * inv + bb[e];
  ((f4*)out)[idx] = o;
}

extern "C" void kernel_launch(void* const* d_in, const int* in_sizes, int n_in,
                              void* d_out, int out_size, void* d_ws, size_t ws_size,
                              hipStream_t stream) {
  const float* x = (const float*)d_in[0];
  const int* adj = (const int*)d_in[1];
  const float* W = (const float*)d_in[2];
  const float* a = (const float*)d_in[3];
  const float* bias = (const float*)d_in[4];
  float* out = (float*)d_out;

  char* ws = (char*)d_ws;
  float* accP = (float*)(ws);                                // 32 MB: 4 chunk-partials
  float* lGp  = (float*)(ws + 33554432);                     // 128 KB: 4 x 8192
  unsigned short* hT  = (unsigned short*)(ws + 33685504);    // 4 MB  [256][8192] bf16
  unsigned short* Whi = (unsigned short*)(ws + 37879808);    // 256 KB [256][512]
  unsigned short* Wlo = (unsigned short*)(ws + 38141952);    // 256 KB
  float* s1 = (float*)(ws + 38404096);                       // 32 KB
  float* s2 = (float*)(ws + 38436864);                       // 32 KB

  k_wsplit<<<512, 256, 0, stream>>>(W, Whi, Wlo);
  k_h<<<512, 64, 0, stream>>>(x, a, Whi, Wlo, hT, s1, s2);
  k_attn<<<1024, 64, 0, stream>>>(adj, s1, s2, hT, accP, lGp);
  k_final<<<2048, 256, 0, stream>>>(accP, lGp, bias, out);
}

// Round 6
// 252.733 us; speedup vs baseline: 1.1024x; 1.1024x over previous
//
#include <hip/hip_runtime.h>

#define NN 8192
#define INF_ 512
#define OUTF 256
#define LOG2E 1.4426950408889634f

typedef __attribute__((ext_vector_type(8))) short short8;
typedef __attribute__((ext_vector_type(4))) short short4v;
typedef __attribute__((ext_vector_type(4))) float f4;
typedef __attribute__((ext_vector_type(4))) int i4;

__device__ __forceinline__ unsigned short f2bf(float f) {
  union { float f; unsigned u; } v; v.f = f;
  unsigned r = v.u + 0x7fffu + ((v.u >> 16) & 1u);
  return (unsigned short)(r >> 16);
}
__device__ __forceinline__ float bf2f(unsigned short h) {
  union { unsigned u; float f; } v; v.u = ((unsigned)h) << 16;
  return v.f;
}

// ---------------- K0: W (512x256 f32) -> W^T hi/lo bf16 (256x512) ----------------
__global__ void k_wsplit(const float* __restrict__ W, unsigned short* __restrict__ Whi,
                         unsigned short* __restrict__ Wlo) {
  int idx = blockIdx.x * 256 + threadIdx.x;   // 131072
  int k = idx >> 8, c = idx & 255;
  float w = W[idx];
  unsigned short hi = f2bf(w);
  unsigned short lo = f2bf(w - bf2f(hi));
  Whi[c * INF_ + k] = hi;
  Wlo[c * INF_ + k] = lo;
}

// ---------------- K1: h = x@W (split-3 bf16 MFMA), h_T bf16, s1, s2 ----------------
// 512 blocks x 1 wave; block b: rows [b*16,+16), ALL 256 cols. a pre-scaled by LOG2E.
__global__ void __launch_bounds__(64) k_h(
    const float* __restrict__ x, const float* __restrict__ a,
    const unsigned short* __restrict__ Whi, const unsigned short* __restrict__ Wlo,
    unsigned short* __restrict__ hT, float* __restrict__ s1, float* __restrict__ s2) {
  const int rowbase = blockIdx.x * 16;
  const int l = threadIdx.x;
  const int r15 = l & 15, kg = l >> 4;

  f4 acc[16];
#pragma unroll
  for (int i = 0; i < 16; ++i) acc[i] = (f4){0.f, 0.f, 0.f, 0.f};

  for (int kk = 0; kk < INF_; kk += 32) {
    const float* xp = x + (rowbase + r15) * INF_ + kk + kg * 8;
    f4 xa = *(const f4*)xp;
    f4 xb = *(const f4*)(xp + 4);
    short8 ahi, alo;
#pragma unroll
    for (int e = 0; e < 8; ++e) {
      float f = (e < 4) ? xa[e] : xb[e - 4];
      unsigned short h = f2bf(f);
      ahi[e] = (short)h;
      alo[e] = (short)f2bf(f - bf2f(h));
    }
#pragma unroll
    for (int cg = 0; cg < 16; ++cg) {
      int col = cg * 16 + r15;
      const short8 bhi = *(const short8*)(Whi + col * INF_ + kk + kg * 8);
      const short8 blo = *(const short8*)(Wlo + col * INF_ + kk + kg * 8);
      acc[cg] = __builtin_amdgcn_mfma_f32_16x16x32_bf16(ahi, bhi, acc[cg], 0, 0, 0);
      acc[cg] = __builtin_amdgcn_mfma_f32_16x16x32_bf16(ahi, blo, acc[cg], 0, 0, 0);
      acc[cg] = __builtin_amdgcn_mfma_f32_16x16x32_bf16(alo, bhi, acc[cg], 0, 0, 0);
    }
  }
  float sp1[4] = {0, 0, 0, 0}, sp2[4] = {0, 0, 0, 0};
#pragma unroll
  for (int cg = 0; cg < 16; ++cg) {
    int col = cg * 16 + r15;
    float a1v = a[col] * LOG2E, a2v = a[OUTF + col] * LOG2E;
#pragma unroll
    for (int r = 0; r < 4; ++r) {
      float v = acc[cg][r];
      hT[col * NN + rowbase + kg * 4 + r] = f2bf(v);
      sp1[r] += v * a1v;
      sp2[r] += v * a2v;
    }
  }
#pragma unroll
  for (int r = 0; r < 4; ++r) {
#pragma unroll
    for (int m = 1; m < 16; m <<= 1) {
      sp1[r] += __shfl_xor(sp1[r], m, 16);
      sp2[r] += __shfl_xor(sp2[r], m, 16);
    }
    if (r15 == 0) {
      s1[rowbase + kg * 4 + r] = sp1[r];
      s2[rowbase + kg * 4 + r] = sp2[r];
    }
  }
}

// ---------------- K2a: w-matrix gen, fully-contiguous streaming ----------------
// 8192 blocks x 256 threads; block = one adj row. Per wave-instruction: 64 lanes
// x 16B = 1KB CONTIGUOUS (the contiguity-hypothesis test). Fuses row-sum lG.
__global__ void __launch_bounds__(256) k_wgen(
    const int* __restrict__ adj, const float* __restrict__ s1G,
    const float* __restrict__ s2G, unsigned short* __restrict__ w,
    float* __restrict__ lG) {
  __shared__ float red[4];
  const int row = blockIdx.x;
  const int tid = threadIdx.x;
  const float s1v = s1G[row];                 // pre-scaled by LOG2E
  const i4* ap = (const i4*)(adj + (size_t)row * NN);
  const f4* sp = (const f4*)s2G;
  unsigned short* wrow = w + (size_t)row * NN;
  float lsum = 0.f;

#pragma unroll
  for (int u = 0; u < 8; ++u) {
    const int q = u * 256 + tid;              // i4/f4 index; bytes contiguous per wave
    i4 m = ap[q];
    f4 sv = sp[q];
    short4v wp;
#pragma unroll
    for (int e = 0; e < 4; ++e) {
      float xx = s1v + sv[e];
      float lr = fmaxf(xx, 0.2f * xx);
      float pp = __builtin_amdgcn_exp2f(lr);
      float w0 = (m[e] > 0) ? pp : 0.0f;
      unsigned short hh = f2bf(w0);
      wp[e] = (short)hh;
      lsum += bf2f(hh);                       // sum ROUNDED weights (exact convex comb.)
    }
    *(short4v*)(wrow + q * 4) = wp;           // 8B/thread, 512B contiguous per wave
  }

  // block reduce -> lG[row]
#pragma unroll
  for (int m = 1; m < 64; m <<= 1) lsum += __shfl_xor(lsum, m, 64);
  if ((tid & 63) == 0) red[tid >> 6] = lsum;
  __syncthreads();
  if (tid == 0) lG[row] = red[0] + red[1] + red[2] + red[3];
}

// ---------------- K2b: GEMM  CP[qt] = w[rows, kq] @ h[kq, cols] ----------------
// 512 blocks x 4 waves: rt=b>>2 (64 rows), qt=b&3 (K-quarter 2048). qt==XCD%4 so
// each XCD's L2 holds one 2MB hT quarter. A(w) staged via global_load_lds with
// pre-swizzled source + XOR-swizzled ds_read_b128 (T2). B issued before glls so
// MFMA auto-wait is vmcnt(4) and glls stay in flight across the phase (T4-lite).
__global__ void __launch_bounds__(256) k_av(
    const unsigned short* __restrict__ w, const unsigned short* __restrict__ hT,
    float* __restrict__ CP) {
  __shared__ unsigned short At[2][8192];     // [64 rows][128 k] bf16, 16KB each, swizzled
  const int b = blockIdx.x;
  const int rt = b >> 2, qt = b & 3;
  const int rowbase = rt * 64;
  const int kbase = qt * 2048;
  const int tid = threadIdx.x;
  const int wv = tid >> 6, l = tid & 63;
  const int r15 = l & 15, kg = l >> 4;
  const int colbase = wv * 64;
  const char* wb = (const char*)w;

#define STAGE_A(buf, t)                                                           \
  {                                                                               \
    _Pragma("unroll")                                                             \
    for (int q = 0; q < 4; ++q) {                                                 \
      const int d = q * 4096 + tid * 16;      /* linear dest byte */              \
      const int r = d >> 8;                   /* tile row */                      \
      const int cb = d & 255;                 /* byte-in-row */                   \
      const int sc = cb ^ ((r & 7) << 4);     /* inverse swizzle on SOURCE */     \
      const char* src = wb + (size_t)(rowbase + r) * (NN * 2) +                   \
                        (size_t)(kbase + (t) * 128) * 2 + sc;                     \
      __builtin_amdgcn_global_load_lds(                                           \
          (const __attribute__((address_space(1))) unsigned int*)src,             \
          (__attribute__((address_space(3))) unsigned int*)                       \
              ((char*)&At[buf][0] + d), 16, 0, 0);                                \
    }                                                                             \
  }

  f4 acc[4][4];
#pragma unroll
  for (int rg = 0; rg < 4; ++rg)
#pragma unroll
    for (int cg = 0; cg < 4; ++cg) acc[rg][cg] = (f4){0.f, 0.f, 0.f, 0.f};

  // prologue
  STAGE_A(0, 0)
  asm volatile("s_waitcnt vmcnt(0)" ::: "memory");
  __builtin_amdgcn_s_barrier();

  int cur = 0;
  for (int t = 0; t < 16; ++t) {
    // ---- issue B(t) FIRST (16 L2 loads; MFMA auto-wait will be vmcnt(4)) ----
    short8 Bf[4][4];
#pragma unroll
    for (int ks = 0; ks < 4; ++ks)
#pragma unroll
      for (int cg = 0; cg < 4; ++cg)
        Bf[ks][cg] = *(const short8*)(hT + (size_t)(colbase + cg * 16 + r15) * NN +
                                      kbase + t * 128 + ks * 32 + kg * 8);
    // ---- issue STAGE(t+1) glls (stay in flight across MFMAs) ----
    if (t < 15) STAGE_A(cur ^ 1, t + 1)
    // ---- A-frags from LDS (swizzled) + 64 MFMAs ----
#pragma unroll
    for (int ks = 0; ks < 4; ++ks)
#pragma unroll
      for (int rg = 0; rg < 4; ++rg) {
        const int r = rg * 16 + r15;
        const int byte = ((r * 256 + ks * 64 + kg * 16) ^ ((r & 7) << 4));
        const short8 Af = *(const short8*)((const char*)&At[cur][0] + byte);
#pragma unroll
        for (int cg = 0; cg < 4; ++cg)
          acc[rg][cg] = __builtin_amdgcn_mfma_f32_16x16x32_bf16(Af, Bf[ks][cg], acc[rg][cg], 0, 0, 0);
      }
    // ---- drain this phase's glls (issued ~full phase ago) and hand off ----
    asm volatile("s_waitcnt vmcnt(0)" ::: "memory");
    __builtin_amdgcn_s_barrier();
    cur ^= 1;
  }

  // epilogue: plain stores to quarter-partial
  float* cp = CP + (size_t)qt * NN * OUTF;
#pragma unroll
  for (int rg = 0; rg < 4; ++rg)
#pragma unroll
    for (int cg = 0; cg < 4; ++cg)
#pragma unroll
      for (int r = 0; r < 4; ++r)
        cp[(size_t)(rowbase + rg * 16 + kg * 4 + r) * OUTF + colbase + cg * 16 + r15] =
            acc[rg][cg][r];
}

// ---------------- K3: out = (sum of 4 K-quarter partials) / l + bias ----------------
__global__ void k_final(const float* __restrict__ CP, const float* __restrict__ lG,
                        const float* __restrict__ bias, float* __restrict__ out) {
  const int idx = blockIdx.x * 256 + threadIdx.x;  // f4 index, 524288 total
  const int row = idx >> 6;
  const int c4 = idx & 63;
  const int CS = NN * OUTF / 4;   // quarter stride in f4
  f4 v0 = ((const f4*)CP)[idx];
  f4 v1 = ((const f4*)CP)[idx + CS];
  f4 v2 = ((const f4*)CP)[idx + 2 * CS];
  f4 v3 = ((const f4*)CP)[idx + 3 * CS];
  float inv = 1.0f / lG[row];
  f4 bb = ((const f4*)bias)[c4];
  f4 o;
#pragma unroll
  for (int e = 0; e < 4; ++e)
    o[e] = (v0[e] + v1[e] + v2[e] + v3[e]) * inv + bb[e];
  ((f4*)out)[idx] = o;
}

extern "C" void kernel_launch(void* const* d_in, const int* in_sizes, int n_in,
                              void* d_out, int out_size, void* d_ws, size_t ws_size,
                              hipStream_t stream) {
  const float* x = (const float*)d_in[0];
  const int* adj = (const int*)d_in[1];
  const float* W = (const float*)d_in[2];
  const float* a = (const float*)d_in[3];
  const float* bias = (const float*)d_in[4];
  float* out = (float*)d_out;

  char* ws = (char*)d_ws;
  unsigned short* w  = (unsigned short*)(ws);                 // 128 MB  [8192][8192] bf16
  float* CP  = (float*)(ws + 134217728);                      // 32 MB   4 x [8192][256] f32
  float* lG  = (float*)(ws + 167772160);                      // 32 KB
  unsigned short* hT  = (unsigned short*)(ws + 167804928);    // 4 MB   [256][8192] bf16
  unsigned short* Whi = (unsigned short*)(ws + 171999232);    // 256 KB [256][512]
  unsigned short* Wlo = (unsigned short*)(ws + 172261376);    // 256 KB
  float* s1 = (float*)(ws + 172523520);                       // 32 KB
  float* s2 = (float*)(ws + 172556288);                       // 32 KB

  k_wsplit<<<512, 256, 0, stream>>>(W, Whi, Wlo);
  k_h<<<512, 64, 0, stream>>>(x, a, Whi, Wlo, hT, s1, s2);
  k_wgen<<<8192, 256, 0, stream>>>(adj, s1, s2, w, lG);
  k_av<<<512, 256, 0, stream>>>(w, hT, CP);
  k_final<<<2048, 256, 0, stream>>>(CP, lG, bias, out);
}